// Round 10
// baseline (246.860 us; speedup 1.0000x reference)
//
#include <hip/hip_runtime.h>

#define BB 4
#define CC 128
#define HH 180
#define WWW 180
#define HWHW (HH*WWW)       // 32400
#define CCAMD 256
#define NHEADS 4
#define HDD 128
#define NT 20000
#define MTOT 80000          // B*N, = 1250 * 64 exactly
#define GAMMA_C 0.08f
#define EPS_C 1e-6f
#define SCALE_C 0.17677669529663687f  // 1/sqrt(32)

typedef short bf16x8 __attribute__((ext_vector_type(8)));
typedef float f32x4 __attribute__((ext_vector_type(4)));

typedef __attribute__((address_space(1))) const unsigned int GU;
typedef __attribute__((address_space(3))) unsigned int LU;

static __device__ __forceinline__ void gll16(const void* g, void* l) {
  __builtin_amdgcn_global_load_lds((GU*)g, (LU*)l, 16, 0, 0);
}

static __device__ __forceinline__ unsigned short f2bf(float x) {
  unsigned int b = __float_as_uint(x);
  unsigned int r = (b + 0x7fffu + ((b >> 16) & 1u)) >> 16;
  return (unsigned short)r;
}
static __device__ __forceinline__ float b2f(unsigned short u) {
  return __uint_as_float(((unsigned int)u) << 16);
}

static __device__ __forceinline__ float warpMax(float v) {
#pragma unroll
  for (int o = 32; o >= 1; o >>= 1) v = fmaxf(v, __shfl_xor(v, o));
  return v;
}
static __device__ __forceinline__ float warpSum(float v) {
#pragma unroll
  for (int o = 32; o >= 1; o >>= 1) v += __shfl_xor(v, o);
  return v;
}

// ---------------------------------------------------------------------------
// k_prep_pix: blocks 0..95: weight f32->bf16; blocks 96..408: pixel indices.
// ---------------------------------------------------------------------------
__global__ __launch_bounds__(256) void k_prep_pix(
    const float* __restrict__ kw, const float* __restrict__ vw,
    const float* __restrict__ qw, const float* __restrict__ ow,
    unsigned short* __restrict__ kvw, unsigned short* __restrict__ qwb,
    unsigned short* __restrict__ owb, const int* __restrict__ cidx,
    int* __restrict__ pix_ws, float* __restrict__ hits)
{
  if (blockIdx.x < 96) {
    const int t = blockIdx.x * 256 + threadIdx.x;  // one float4 per thread
    float4 f;
    unsigned short* dst;
    if (t < 16384) {           // kv: 65536 elems
      f = (t < 8192) ? ((const float4*)kw)[t] : ((const float4*)vw)[t - 8192];
      dst = kvw + (size_t)t * 4;
    } else if (t < 20480) {    // q: 16384 elems
      const int i = t - 16384;
      f = ((const float4*)qw)[i];
      dst = qwb + (size_t)i * 4;
    } else {                   // out: 16384 elems
      const int i = t - 20480;
      f = ((const float4*)ow)[i];
      dst = owb + (size_t)i * 4;
    }
    ushort4 u;
    u.x = f2bf(f.x); u.y = f2bf(f.y); u.z = f2bf(f.z); u.w = f2bf(f.w);
    *(ushort4*)dst = u;
  } else {
    const int t = (blockIdx.x - 96) * 256 + threadIdx.x;
    if (t >= MTOT) return;
    const int2 ij = *(const int2*)(cidx + (size_t)t * 2);
    int ii = ij.x; ii = ii < 0 ? 0 : (ii > HH - 1 ? HH - 1 : ii);
    int jj = ij.y; jj = jj < 0 ? 0 : (jj > WWW - 1 ? WWW - 1 : jj);
    const int pix = ii * WWW + jj;
    pix_ws[t] = pix;
    atomicAdd(hits + (size_t)(t / NT) * HWHW + pix, 1.0f);
  }
}

// ---------------------------------------------------------------------------
// k_tr2: lidar_t[b][p][c] (bf16) = lidar[b][c][p].
// ---------------------------------------------------------------------------
__global__ __launch_bounds__(256) void k_tr2(
    const float* __restrict__ lidar, unsigned short* __restrict__ lidar_t)
{
  const int b = blockIdx.y;
  const int p = blockIdx.x * 256 + threadIdx.x;
  if (p >= HWHW) return;
  const int z = blockIdx.z;  // channel half
  const float* src = lidar + ((size_t)b * CC + z * 64) * HWHW + p;
  unsigned short* dst = lidar_t + ((size_t)b * HWHW + p) * 128 + z * 64;
#pragma unroll
  for (int c8 = 0; c8 < 8; ++c8) {
    bf16x8 v;
#pragma unroll
    for (int e = 0; e < 8; ++e)
      v[e] = (short)f2bf(src[(size_t)(c8 * 8 + e) * HWHW]);
    ((bf16x8*)dst)[c8] = v;
  }
}

// ---------------------------------------------------------------------------
// k_zero: zero only HIT delta rows (idempotent concurrent zero-writes).
// ---------------------------------------------------------------------------
__global__ __launch_bounds__(256) void k_zero(
    const int* __restrict__ pix_ws, float* __restrict__ delta)
{
  const int t = blockIdx.x * 256 + threadIdx.x;
  const int ng = t >> 5, l32 = t & 31;
  const int b = ng / NT;
  const int pix = pix_ws[ng];
  *(float4*)(delta + ((size_t)b * HWHW + pix) * 128 + l32 * 4) =
      make_float4(0.0f, 0.0f, 0.0f, 0.0f);
}

// ---------------------------------------------------------------------------
// k_pfused: per 64-token block —
//  Phase A: [64,256] = tokens[64,256] x kvw^T (K cols 0..127 -> LDS,
//           V cols 128..255 -> v_bf global). A LDS-staged dbuf; B direct L2.
//  Phase B: q[64,128] = gathered lidar_t rows x qw^T; logits = (q+bias).K
//           with K read from LDS. 8 waves; A tiles 64x64; XOR-swizzled LDS.
// ---------------------------------------------------------------------------
__global__ __launch_bounds__(512) void k_pfused(
    const float* __restrict__ tokens,
    const unsigned short* __restrict__ lidar_t,
    const int* __restrict__ pixw,
    const unsigned short* __restrict__ kvw,
    const unsigned short* __restrict__ qwb,
    const float* __restrict__ qb,
    unsigned short* __restrict__ v_bf,
    float* __restrict__ logits)
{
  __shared__ unsigned short lds[16384];  // [0,8192): A dbuf 2x4096; [8192,16384): K 64x128
  const int tid = threadIdx.x;
  const int lane = tid & 63, wave = tid >> 6;
  const int wm = wave >> 2, wn = wave & 3;
  const int l16 = lane & 15, kg = lane >> 4;
  const int g3 = lane >> 3, c8l = lane & 7;
  const int mblk = blockIdx.x;
  const int rstage = mblk * 64 + wave * 8 + g3;

  // ================= phase A: kv projection =================
  f32x4 acc[2][4];
#pragma unroll
  for (int i = 0; i < 2; ++i)
#pragma unroll
    for (int j = 0; j < 4; ++j) acc[i][j] = (f32x4)0.0f;

  const float* ap = tokens + (size_t)rstage * CCAMD + c8l * 8;
  bf16x8 areg;

  auto loadA = [&](int kt) {
    const float4 f0 = *(const float4*)(ap + kt * 64);
    const float4 f1 = *(const float4*)(ap + kt * 64 + 4);
    bf16x8 v;
    v[0] = (short)f2bf(f0.x); v[1] = (short)f2bf(f0.y);
    v[2] = (short)f2bf(f0.z); v[3] = (short)f2bf(f0.w);
    v[4] = (short)f2bf(f1.x); v[5] = (short)f2bf(f1.y);
    v[6] = (short)f2bf(f1.z); v[7] = (short)f2bf(f1.w);
    areg = v;
  };
  auto writeA = [&](int nb) {
    *(bf16x8*)&lds[nb * 4096 + (wave * 8 + g3) * 64 + (c8l ^ g3) * 8] = areg;
  };
  auto computeA = [&](int kt, int cb) {
#pragma unroll
    for (int ks = 0; ks < 2; ++ks) {
      const int swz = ((ks * 4 + kg) ^ (l16 & 7)) * 8;
      bf16x8 a[2], b[4];
#pragma unroll
      for (int mf = 0; mf < 2; ++mf)
        a[mf] = *(const bf16x8*)&lds[cb * 4096 + (wm * 32 + mf * 16 + l16) * 64 + swz];
#pragma unroll
      for (int nf = 0; nf < 4; ++nf)
        b[nf] = *(const bf16x8*)(kvw + (size_t)(wn * 64 + nf * 16 + l16) * CCAMD +
                                 kt * 64 + ks * 32 + kg * 8);
#pragma unroll
      for (int mf = 0; mf < 2; ++mf)
#pragma unroll
        for (int nf = 0; nf < 4; ++nf)
          acc[mf][nf] =
              __builtin_amdgcn_mfma_f32_16x16x32_bf16(a[mf], b[nf], acc[mf][nf], 0, 0, 0);
    }
  };

  loadA(0); writeA(0);
  __syncthreads();
  int cur = 0;
#pragma unroll
  for (int kt = 0; kt < 4; ++kt) {
    if (kt + 1 < 4) loadA(kt + 1);
    computeA(kt, cur);
    if (kt + 1 < 4) writeA(cur ^ 1);
    __syncthreads();
    cur ^= 1;
  }

  // phase A epilogue: K -> LDS, V -> global
  if (wn < 2) {
#pragma unroll
    for (int mf = 0; mf < 2; ++mf)
#pragma unroll
      for (int j = 0; j < 4; ++j) {
        const int rl = wm * 32 + mf * 16 + kg * 4 + j;
#pragma unroll
        for (int nf = 0; nf < 4; ++nf)
          lds[8192 + rl * 128 + wn * 64 + nf * 16 + l16] = f2bf(acc[mf][nf][j]);
      }
  } else {
#pragma unroll
    for (int mf = 0; mf < 2; ++mf)
#pragma unroll
      for (int j = 0; j < 4; ++j) {
        const int row = mblk * 64 + wm * 32 + mf * 16 + kg * 4 + j;
        unsigned short* dr = v_bf + (size_t)row * 128 + (wn - 2) * 64 + l16;
#pragma unroll
        for (int nf = 0; nf < 4; ++nf) dr[nf * 16] = f2bf(acc[mf][nf][j]);
      }
  }

  // ================= phase B: q projection + logits =================
  const int bbr = rstage / NT;
  const unsigned short* garow =
      lidar_t + ((size_t)bbr * HWHW + pixw[rstage]) * 128 + (c8l ^ g3) * 8;

  f32x4 qacc[2][2];
#pragma unroll
  for (int i = 0; i < 2; ++i)
#pragma unroll
    for (int j = 0; j < 2; ++j) qacc[i][j] = (f32x4)0.0f;

  auto computeB = [&](int kt, int cb) {
#pragma unroll
    for (int ks = 0; ks < 2; ++ks) {
      const int swz = ((ks * 4 + kg) ^ (l16 & 7)) * 8;
      bf16x8 a[2], b[2];
#pragma unroll
      for (int mf = 0; mf < 2; ++mf)
        a[mf] = *(const bf16x8*)&lds[cb * 4096 + (wm * 32 + mf * 16 + l16) * 64 + swz];
#pragma unroll
      for (int nf = 0; nf < 2; ++nf)
        b[nf] = *(const bf16x8*)(qwb + (size_t)(wn * 32 + nf * 16 + l16) * HDD +
                                 kt * 64 + ks * 32 + kg * 8);
#pragma unroll
      for (int mf = 0; mf < 2; ++mf)
#pragma unroll
        for (int nf = 0; nf < 2; ++nf)
          qacc[mf][nf] =
              __builtin_amdgcn_mfma_f32_16x16x32_bf16(a[mf], b[nf], qacc[mf][nf], 0, 0, 0);
    }
  };

  gll16(garow, &lds[wave * 512]);                 // stage tile0 -> buf0
  __syncthreads();                                // also orders K-LDS writes
  gll16(garow + 64, &lds[4096 + wave * 512]);     // stage tile1 -> buf1
  computeB(0, 0);
  __syncthreads();
  computeB(1, 1);
  __syncthreads();

  // logits epilogue: logit[row][h=wn] = SCALE * sum_d (q+bias)*K_lds
  float* scratch = (float*)lds;   // buf region, free now
  float bv[2];
#pragma unroll
  for (int nf = 0; nf < 2; ++nf) bv[nf] = qb[wn * 32 + nf * 16 + l16];
#pragma unroll
  for (int mf = 0; mf < 2; ++mf) {
#pragma unroll
    for (int j = 0; j < 4; ++j) {
      const int rl = wm * 32 + mf * 16 + kg * 4 + j;
      float s =
          (qacc[mf][0][j] + bv[0]) * b2f(lds[8192 + rl * 128 + wn * 32 + l16]) +
          (qacc[mf][1][j] + bv[1]) * b2f(lds[8192 + rl * 128 + wn * 32 + 16 + l16]);
      s += __shfl_xor(s, 8, 16); s += __shfl_xor(s, 4, 16);
      s += __shfl_xor(s, 2, 16); s += __shfl_xor(s, 1, 16);
      if (l16 == 0) scratch[rl * 4 + wn] = s;
    }
  }
  __syncthreads();
  if (tid < 64) {
    const int row = mblk * 64 + tid;
    const int bb = row / NT, n = row - bb * NT;
#pragma unroll
    for (int h = 0; h < 4; ++h)
      logits[((size_t)bb * NHEADS + h) * NT + n] = scratch[tid * 4 + h] * SCALE_C;
  }
}

// ---------------------------------------------------------------------------
// k_outp: out_tok = out_w x (softmax*gate*V) per token; atomic scatter into
// delta[B][HW][128] + column sums -> meanr. M-tile 64, A reg-staged with
// coef, B (out_w, 32KB) direct from L2.
// ---------------------------------------------------------------------------
__global__ __launch_bounds__(512) void k_outp(
    const unsigned short* __restrict__ v_bf, const unsigned short* __restrict__ owb,
    const int* __restrict__ pixw, const float* __restrict__ smMp,
    const float* __restrict__ smSinvp, const float* __restrict__ gatep,
    const float* __restrict__ logp, float* __restrict__ delta,
    float* __restrict__ meanr)
{
  __shared__ unsigned short lds[8192];  // A dbuf 2x4096
  const int tid = threadIdx.x;
  const int lane = tid & 63, wave = tid >> 6;
  const int wm = wave >> 2, wn = wave & 3;
  const int l16 = lane & 15, kg = lane >> 4;
  const int g3 = lane >> 3, c8l = lane & 7;
  const int mblk = blockIdx.x;
  const int rstage = mblk * 64 + wave * 8 + g3;
  const int bbr = rstage / NT, nr = rstage - bbr * NT;
  const unsigned short* vrow = v_bf + (size_t)rstage * 128 + c8l * 8;
  const float ga = gatep[(size_t)bbr * NT + nr];

  f32x4 acc[2][2];
#pragma unroll
  for (int i = 0; i < 2; ++i)
#pragma unroll
    for (int j = 0; j < 2; ++j) acc[i][j] = (f32x4)0.0f;

  bf16x8 areg;
  auto loadA = [&](int kt) {
    const int h = kt * 2 + (c8l >> 2);
    const int bh = bbr * NHEADS + h;
    const float coef =
        __expf(logp[((size_t)bbr * NHEADS + h) * NT + nr] - smMp[bh]) * smSinvp[bh] * ga;
    const bf16x8 v = *(const bf16x8*)(vrow + kt * 64);
    bf16x8 o;
#pragma unroll
    for (int e = 0; e < 8; ++e) o[e] = (short)f2bf(b2f((unsigned short)v[e]) * coef);
    areg = o;
  };
  auto writeA = [&](int nb) {
    *(bf16x8*)&lds[nb * 4096 + (wave * 8 + g3) * 64 + (c8l ^ g3) * 8] = areg;
  };
  auto compute = [&](int kt, int cb) {
#pragma unroll
    for (int ks = 0; ks < 2; ++ks) {
      const int swz = ((ks * 4 + kg) ^ (l16 & 7)) * 8;
      bf16x8 a[2], b[2];
#pragma unroll
      for (int mf = 0; mf < 2; ++mf)
        a[mf] = *(const bf16x8*)&lds[cb * 4096 + (wm * 32 + mf * 16 + l16) * 64 + swz];
#pragma unroll
      for (int nf = 0; nf < 2; ++nf)
        b[nf] = *(const bf16x8*)(owb + (size_t)(wn * 32 + nf * 16 + l16) * HDD +
                                 kt * 64 + ks * 32 + kg * 8);
#pragma unroll
      for (int mf = 0; mf < 2; ++mf)
#pragma unroll
        for (int nf = 0; nf < 2; ++nf)
          acc[mf][nf] =
              __builtin_amdgcn_mfma_f32_16x16x32_bf16(a[mf], b[nf], acc[mf][nf], 0, 0, 0);
    }
  };

  loadA(0); writeA(0);
  __syncthreads();
  loadA(1);
  compute(0, 0);
  writeA(1);
  __syncthreads();
  compute(1, 1);
  __syncthreads();

  // epilogue: scatter + column sums
  float* scratch = (float*)lds;
  if (tid < 256) scratch[tid] = 0.0f;
  __syncthreads();
  const int b0 = (mblk * 64) / NT;
#pragma unroll
  for (int mf = 0; mf < 2; ++mf) {
    const int baser = mblk * 64 + wm * 32 + mf * 16 + kg * 4;
    const int bbq = baser / NT;          // uniform over j (NT % 4 == 0)
    const int bsel = (bbq != b0) ? 1 : 0;
    float s[2] = {0.0f, 0.0f};
#pragma unroll
    for (int j = 0; j < 4; ++j) {
      const int row = baser + j;
      const int pix = pixw[row];
      float* dr = delta + ((size_t)bbq * HWHW + pix) * 128 + wn * 32 + l16;
#pragma unroll
      for (int nf = 0; nf < 2; ++nf) {
        atomicAdd(dr + nf * 16, acc[mf][nf][j]);
        s[nf] += acc[mf][nf][j];
      }
    }
#pragma unroll
    for (int nf = 0; nf < 2; ++nf)
      atomicAdd(&scratch[bsel * 128 + wn * 32 + nf * 16 + l16], s[nf]);
  }
  __syncthreads();
  const int b1 = (mblk * 64 + 63) / NT;
  if (tid < 128) atomicAdd(meanr + (size_t)b0 * 128 + tid, scratch[tid]);
  else if (tid < 256 && b1 != b0)
    atomicAdd(meanr + (size_t)b1 * 128 + (tid - 128), scratch[tid]);
}

// ---------------------------------------------------------------------------
// k_smpart: per-(bh, chunk) partial max & sum-exp.  NT = 8 * 2500.
// ---------------------------------------------------------------------------
__global__ __launch_bounds__(256) void k_smpart(
    const float* __restrict__ logits, float* __restrict__ pm,
    float* __restrict__ ps)
{
  const int ch = blockIdx.x, bh = blockIdx.y;
  const float* L = logits + (size_t)bh * NT + ch * 2500;
  const int tid = threadIdx.x;
  __shared__ float sred[4];

  float m = -INFINITY;
  for (int i = tid; i < 2500; i += 256) m = fmaxf(m, L[i]);
  m = warpMax(m);
  if ((tid & 63) == 0) sred[tid >> 6] = m;
  __syncthreads();
  m = fmaxf(fmaxf(sred[0], sred[1]), fmaxf(sred[2], sred[3]));

  float s = 0.0f;
  for (int i = tid; i < 2500; i += 256) s += __expf(L[i] - m);
  s = warpSum(s);
  __syncthreads();
  if ((tid & 63) == 0) sred[tid >> 6] = s;
  __syncthreads();
  if (tid == 0) {
    pm[bh * 8 + ch] = m;
    ps[bh * 8 + ch] = sred[0] + sred[1] + sred[2] + sred[3];
  }
}

// ---------------------------------------------------------------------------
// k_cntfix: block b: cnt[b] = #hit pixels. Block 0 also combines softmax
// partials -> smM, smSinv.
// ---------------------------------------------------------------------------
__global__ __launch_bounds__(256) void k_cntfix(
    const float* __restrict__ hits, float* __restrict__ cnt,
    const float* __restrict__ pm, const float* __restrict__ ps,
    float* __restrict__ smM, float* __restrict__ smSinv)
{
  const int b = blockIdx.x;
  const int tid = threadIdx.x;
  float s = 0.0f;
  for (int i = tid; i < HWHW; i += 256)
    s += (hits[(size_t)b * HWHW + i] > 0.0f) ? 1.0f : 0.0f;
  s = warpSum(s);
  __shared__ float sred[4];
  if ((tid & 63) == 0) sred[tid >> 6] = s;
  __syncthreads();
  if (tid == 0) cnt[b] = sred[0] + sred[1] + sred[2] + sred[3];
  if (b == 0 && tid < BB * NHEADS) {
    float M = -INFINITY;
#pragma unroll
    for (int c = 0; c < 8; ++c) M = fmaxf(M, pm[tid * 8 + c]);
    float S = 0.0f;
#pragma unroll
    for (int c = 0; c < 8; ++c) S += ps[tid * 8 + c] * __expf(pm[tid * 8 + c] - M);
    smM[tid] = M;
    smSinv[tid] = 1.0f / S;
  }
}

// ---------------------------------------------------------------------------
// k_final: out[b][c][hw] = lidar + (delta[b][hw][c] - mean*mask)*alpha*gamma
// 80px x 128ch tiles, 512 threads; hits-gated delta reads; XOR-swizzled LDS.
// ---------------------------------------------------------------------------
__global__ __launch_bounds__(512) void k_final(
    const float* __restrict__ lidar, const float* __restrict__ alpha,
    const float* __restrict__ hits, const float* __restrict__ mean_raw,
    const float* __restrict__ cnt, const float* __restrict__ delta,
    float* __restrict__ out)
{
  __shared__ float tile[80 * 136];
  const int b = blockIdx.y;
  const int p0 = blockIdx.x * 80;
  const int t = threadIdx.x;
  const float4* dsrc = (const float4*)(delta + ((size_t)b * HWHW + p0) * 128);
  const float* hrow = hits + (size_t)b * HWHW + p0;
#pragma unroll
  for (int i = 0; i < 5; ++i) {
    const int idx4 = i * 512 + t;         // 2560 float4 = 80px * 32
    const int p = idx4 >> 5, c4 = idx4 & 31;
    float4 f = make_float4(0.0f, 0.0f, 0.0f, 0.0f);
    if (hrow[p] > 0.0f) f = dsrc[idx4];
    *(float4*)&tile[p * 136 + ((c4 ^ (p & 7)) << 2)] = f;
  }
  __syncthreads();
  const int c = t >> 2, sub = t & 3;
  const int cq = c >> 2, cr = c & 3;
  const float mn = mean_raw[b * 128 + c] / (cnt[b] + EPS_C);
  const size_t cbase = ((size_t)b * CC + c) * HWHW + p0;
  const size_t hbase = (size_t)b * HWHW + p0;
#pragma unroll
  for (int j = 0; j < 5; ++j) {
    const int pq = j * 16 + sub * 4;
    float4 d;
    d.x = tile[(pq + 0) * 136 + (((cq ^ ((pq + 0) & 7)) << 2) | cr)];
    d.y = tile[(pq + 1) * 136 + (((cq ^ ((pq + 1) & 7)) << 2) | cr)];
    d.z = tile[(pq + 2) * 136 + (((cq ^ ((pq + 2) & 7)) << 2) | cr)];
    d.w = tile[(pq + 3) * 136 + (((cq ^ ((pq + 3) & 7)) << 2) | cr)];
    const float4 li = *(const float4*)(lidar + cbase + pq);
    const float4 al = *(const float4*)(alpha + p0 + pq);
    const float4 ht = *(const float4*)(hits + hbase + pq);
    float4 o;
    o.x = li.x + (d.x - (ht.x > 0.0f ? mn : 0.0f)) * al.x * GAMMA_C;
    o.y = li.y + (d.y - (ht.y > 0.0f ? mn : 0.0f)) * al.y * GAMMA_C;
    o.z = li.z + (d.z - (ht.z > 0.0f ? mn : 0.0f)) * al.z * GAMMA_C;
    o.w = li.w + (d.w - (ht.w > 0.0f ? mn : 0.0f)) * al.w * GAMMA_C;
    *(float4*)(out + cbase + pq) = o;
  }
}

// ---------------------------------------------------------------------------
extern "C" void kernel_launch(void* const* d_in, const int* in_sizes, int n_in,
                              void* d_out, int out_size, void* d_ws, size_t ws_size,
                              hipStream_t stream)
{
  const float* lidar  = (const float*)d_in[0];
  const float* tokens = (const float*)d_in[1];
  const float* gate   = (const float*)d_in[2];
  const float* alpha  = (const float*)d_in[3];
  const float* q_w    = (const float*)d_in[4];
  const float* q_b    = (const float*)d_in[5];
  const float* k_w    = (const float*)d_in[6];
  const float* v_w    = (const float*)d_in[7];
  const float* out_w  = (const float*)d_in[8];
  const int*   cidx   = (const int*)d_in[9];
  float* out = (float*)d_out;

  char* W = (char*)d_ws;
  // v_bf [80000][128] bf16 : 20,480,000 B
  unsigned short* v_bf = (unsigned short*)(W + 0);
  // delta [B][HW][128] f32 (66,355,200). lidar_t aliases its tail region and
  // is dead before k_zero touches delta.
  float* delta = (float*)(W + 61440000);
  unsigned short* lidar_t = (unsigned short*)(W + 81920000);
  float* logits   = (float*)(W + 127795200);   // 1,280,000
  int*   pix_ws   = (int*)(W + 129075200);     //   320,000
  float* hits     = (float*)(W + 129395200);   //   518,400
  float* mean_raw = (float*)(W + 129913600);   //     2,048
  float* cnt      = (float*)(W + 129915648);   //        64
  unsigned short* kvw_bf = (unsigned short*)(W + 129915712);  // 131,072
  unsigned short* qw_bf  = (unsigned short*)(W + 130046784);  //  32,768
  unsigned short* ow_bf  = (unsigned short*)(W + 130079552);  //  32,768
  float* pm     = (float*)(W + 130112320);     // 512
  float* ps     = (float*)(W + 130112832);     // 512
  float* smM    = (float*)(W + 130113344);     // 64
  float* smSinv = (float*)(W + 130113408);     // 64

  hipMemsetAsync(hits, 0, (size_t)BB * HWHW * sizeof(float), stream);
  hipMemsetAsync(mean_raw, 0, 2048 + 64, stream);

  k_prep_pix<<<dim3(409), 256, 0, stream>>>(k_w, v_w, q_w, out_w, kvw_bf,
                                            qw_bf, ow_bf, cidx, pix_ws, hits);
  k_tr2<<<dim3(127, BB, 2), 256, 0, stream>>>(lidar, lidar_t);
  // fused kv-proj + q-proj + logits
  k_pfused<<<dim3(1250), 512, 0, stream>>>(tokens, lidar_t, pix_ws, kvw_bf,
                                           qw_bf, q_b, v_bf, logits);
  // lidar_t dead from here: zero only hit delta rows
  k_zero<<<dim3(10000), 256, 0, stream>>>(pix_ws, delta);
  k_smpart<<<dim3(8, BB * NHEADS), 256, 0, stream>>>(logits, pm, ps);
  k_cntfix<<<dim3(BB), 256, 0, stream>>>(hits, cnt, pm, ps, smM, smSinv);
  // out projection with fused attention-weighted V + scatter + mean accum
  k_outp<<<dim3(1250), 512, 0, stream>>>(v_bf, ow_bf, pix_ws, smM, smSinv,
                                         gate, logits, delta, mean_raw);
  k_final<<<dim3(405, BB), 512, 0, stream>>>(lidar, alpha, hits, mean_raw, cnt,
                                             delta, out);
}

// Round 11
// 221.625 us; speedup vs baseline: 1.1139x; 1.1139x over previous
//
#include <hip/hip_runtime.h>

#define BB 4
#define CC 128
#define HH 180
#define WWW 180
#define HWHW (HH*WWW)       // 32400
#define CCAMD 256
#define NHEADS 4
#define HDD 128
#define NT 20000
#define MTOT 80000          // B*N, = 625 * 128 exactly
#define GAMMA_C 0.08f
#define EPS_C 1e-6f
#define SCALE_C 0.17677669529663687f  // 1/sqrt(32)

typedef short bf16x8 __attribute__((ext_vector_type(8)));
typedef float f32x4 __attribute__((ext_vector_type(4)));

typedef __attribute__((address_space(1))) const unsigned int GU;
typedef __attribute__((address_space(3))) unsigned int LU;

static __device__ __forceinline__ void gll16(const void* g, void* l) {
  __builtin_amdgcn_global_load_lds((GU*)g, (LU*)l, 16, 0, 0);
}

#define WAIT_VMCNT0() asm volatile("s_waitcnt vmcnt(0)" ::: "memory")
#define WAIT_VMCNT2() asm volatile("s_waitcnt vmcnt(2)" ::: "memory")
#define WAIT_VMCNT3() asm volatile("s_waitcnt vmcnt(3)" ::: "memory")
#define WAIT_LGKM0()  asm volatile("s_waitcnt lgkmcnt(0)" ::: "memory")

static __device__ __forceinline__ unsigned short f2bf(float x) {
  unsigned int b = __float_as_uint(x);
  unsigned int r = (b + 0x7fffu + ((b >> 16) & 1u)) >> 16;
  return (unsigned short)r;
}
static __device__ __forceinline__ float b2f(unsigned short u) {
  return __uint_as_float(((unsigned int)u) << 16);
}

static __device__ __forceinline__ float warpMax(float v) {
#pragma unroll
  for (int o = 32; o >= 1; o >>= 1) v = fmaxf(v, __shfl_xor(v, o));
  return v;
}
static __device__ __forceinline__ float warpSum(float v) {
#pragma unroll
  for (int o = 32; o >= 1; o >>= 1) v += __shfl_xor(v, o);
  return v;
}

// ---------------------------------------------------------------------------
// k_prep_pix: blocks 0..95: weight f32->bf16; blocks 96..408: pixel indices.
// ---------------------------------------------------------------------------
__global__ __launch_bounds__(256) void k_prep_pix(
    const float* __restrict__ kw, const float* __restrict__ vw,
    const float* __restrict__ qw, const float* __restrict__ ow,
    unsigned short* __restrict__ kvw, unsigned short* __restrict__ qwb,
    unsigned short* __restrict__ owb, const int* __restrict__ cidx,
    int* __restrict__ pix_ws, float* __restrict__ hits)
{
  if (blockIdx.x < 96) {
    const int t = blockIdx.x * 256 + threadIdx.x;  // one float4 per thread
    float4 f;
    unsigned short* dst;
    if (t < 16384) {           // kv: 65536 elems
      f = (t < 8192) ? ((const float4*)kw)[t] : ((const float4*)vw)[t - 8192];
      dst = kvw + (size_t)t * 4;
    } else if (t < 20480) {    // q: 16384 elems
      const int i = t - 16384;
      f = ((const float4*)qw)[i];
      dst = qwb + (size_t)i * 4;
    } else {                   // out: 16384 elems
      const int i = t - 20480;
      f = ((const float4*)ow)[i];
      dst = owb + (size_t)i * 4;
    }
    ushort4 u;
    u.x = f2bf(f.x); u.y = f2bf(f.y); u.z = f2bf(f.z); u.w = f2bf(f.w);
    *(ushort4*)dst = u;
  } else {
    const int t = (blockIdx.x - 96) * 256 + threadIdx.x;
    if (t >= MTOT) return;
    const int2 ij = *(const int2*)(cidx + (size_t)t * 2);
    int ii = ij.x; ii = ii < 0 ? 0 : (ii > HH - 1 ? HH - 1 : ii);
    int jj = ij.y; jj = jj < 0 ? 0 : (jj > WWW - 1 ? WWW - 1 : jj);
    const int pix = ii * WWW + jj;
    pix_ws[t] = pix;
    atomicAdd(hits + (size_t)(t / NT) * HWHW + pix, 1.0f);
  }
}

// ---------------------------------------------------------------------------
// k_tr2: lidar_t[b][p][c] (bf16) = lidar[b][c][p].
// ---------------------------------------------------------------------------
__global__ __launch_bounds__(256) void k_tr2(
    const float* __restrict__ lidar, unsigned short* __restrict__ lidar_t)
{
  const int b = blockIdx.y;
  const int p = blockIdx.x * 256 + threadIdx.x;
  if (p >= HWHW) return;
  const int z = blockIdx.z;  // channel half
  const float* src = lidar + ((size_t)b * CC + z * 64) * HWHW + p;
  unsigned short* dst = lidar_t + ((size_t)b * HWHW + p) * 128 + z * 64;
#pragma unroll
  for (int c8 = 0; c8 < 8; ++c8) {
    bf16x8 v;
#pragma unroll
    for (int e = 0; e < 8; ++e)
      v[e] = (short)f2bf(src[(size_t)(c8 * 8 + e) * HWHW]);
    ((bf16x8*)dst)[c8] = v;
  }
}

// ---------------------------------------------------------------------------
// k_zero: zero only HIT delta rows (idempotent concurrent zero-writes).
// ---------------------------------------------------------------------------
__global__ __launch_bounds__(256) void k_zero(
    const int* __restrict__ pix_ws, float* __restrict__ delta)
{
  const int t = blockIdx.x * 256 + threadIdx.x;
  const int ng = t >> 5, l32 = t & 31;
  const int b = ng / NT;
  const int pix = pix_ws[ng];
  *(float4*)(delta + ((size_t)b * HWHW + pix) * 128 + l32 * 4) =
      make_float4(0.0f, 0.0f, 0.0f, 0.0f);
}

// ---------------------------------------------------------------------------
// k_pipe: pipelined GEMM C[M,128cols@nblk] = A[M,KW] x W^T (MFMA 16x16x32).
// BM=128, BN=128, BK=32, 512 thr (8 waves 2x4, acc[4][2]).
// 3 LDS buffers (48KB), 2-tiles-ahead prefetch, counted vmcnt (never 0 in
// steady state), raw s_barrier (T3+T4). A reg-staged (AMODE 0/3) or gll16
// (AMODE 2); B always gll16 with source-side XOR swizzle; reads use the
// matching swizzle (2-way banks = free).
// AMODE 0: A f32 rows (tokens), cvt at staging.
// AMODE 2: A bf16 rows gathered from lidar_t via pixw (pre-swizzled source).
// AMODE 3: A = V-half of kv_bf x softmax(logit[h=kt])*gate (coef at staging).
// EPI 0: store bf16 rows to Dbf[row][NOUT]+nblk*128.
// EPI 1: atomic f32 scatter into delta[B][HW][128] + column sums -> meanr.
// EPI 2: per-head logits vs K-half of kvb (wave wn == head), + bias.
// ---------------------------------------------------------------------------
template<int KSTEPS, int KW, int AMODE, int EPI, int NOUT>
__global__ __launch_bounds__(512) void k_pipe(
    const float* __restrict__ Af32, const unsigned short* __restrict__ Abf,
    const unsigned short* __restrict__ Bw, const float* __restrict__ bias,
    unsigned short* __restrict__ Dbf, const int* __restrict__ pixw,
    float* __restrict__ aux,            // EPI1: delta; EPI2: logits out
    const unsigned short* __restrict__ kvb, float* __restrict__ meanr,
    const float* __restrict__ smMp, const float* __restrict__ smSinvp,
    const float* __restrict__ gatep, const float* __restrict__ logp)
{
  __shared__ unsigned short lds[24576];  // 3 bufs x (A 4096 + B 4096) ushorts
  const int tid = threadIdx.x;
  const int lane = tid & 63, wave = tid >> 6;   // 8 waves
  const int wm = wave >> 2, wn = wave & 3;      // 2 x 4
  const int l16 = lane & 15, kg = lane >> 4;
  const int mblk = blockIdx.x, nblk = blockIdx.y;
  const int sr_rd = (l16 >> 1) & 3;             // read-side swizzle key

  // staging geometry: each thread owns one 16B chunk of one row
  const int row_s = wave * 16 + (lane >> 2);    // 0..127
  const int chunk_s = lane & 3;
  const int swz_s = chunk_s ^ ((lane >> 3) & 3);  // == chunk ^ ((row_s>>1)&3)
  const int a_dst = row_s * 32 + swz_s * 8;       // ushort idx (swizzled dest)

  // B source: pre-swizzled col so linear gll16 dest matches read swizzle
  const unsigned short* bsrc = Bw + (size_t)(nblk * 128 + row_s) * KW + swz_s * 8;

  // A sources
  const float* asrc_f32 = nullptr;
  const unsigned short* asrc_bf = nullptr;   // AMODE2 (pre-swz col) / AMODE3 (linear col)
  float coef4[4] = {0.f, 0.f, 0.f, 0.f};
  if constexpr (AMODE == 0) {
    asrc_f32 = Af32 + (size_t)(mblk * 128 + row_s) * KW + chunk_s * 8;
  } else if constexpr (AMODE == 2) {
    const int r = mblk * 128 + row_s;
    const int bb = r / NT;
    asrc_bf = Abf + ((size_t)bb * HWHW + pixw[r]) * 128 + swz_s * 8;
  } else {  // AMODE 3
    const int r = mblk * 128 + row_s;
    const int bb = r / NT, n = r - bb * NT;
    asrc_bf = Abf + (size_t)r * 256 + 128 + chunk_s * 8;
    const float ga = gatep[(size_t)bb * NT + n];
#pragma unroll
    for (int h = 0; h < 4; ++h) {
      const int bh = bb * NHEADS + h;
      coef4[h] = __expf(logp[(size_t)bh * NT + n] - smMp[bh]) * smSinvp[bh] * ga;
    }
  }

  f32x4 acc[4][2];
#pragma unroll
  for (int i = 0; i < 4; ++i)
#pragma unroll
    for (int j = 0; j < 2; ++j) acc[i][j] = (f32x4)0.0f;

  // in-flight A registers, two sets
  float4 afx[2], afy[2];   // AMODE 0
  bf16x8 av[2];            // AMODE 3

  auto issueA = [&](int kt, int s, int buf) {
    if constexpr (AMODE == 0) {
      afx[s] = *(const float4*)(asrc_f32 + kt * 32);
      afy[s] = *(const float4*)(asrc_f32 + kt * 32 + 4);
    } else if constexpr (AMODE == 2) {
      gll16(asrc_bf + kt * 32, &lds[buf * 8192 + wave * 512]);
    } else {
      av[s] = *(const bf16x8*)(asrc_bf + kt * 32);
    }
  };
  auto issueB = [&](int kt, int buf) {
    gll16(bsrc + kt * 32, &lds[buf * 8192 + 4096 + wave * 512]);
  };
  auto writeA = [&](int kt, int s, int buf) {
    bf16x8 v;
    if constexpr (AMODE == 0) {
      v[0] = (short)f2bf(afx[s].x); v[1] = (short)f2bf(afx[s].y);
      v[2] = (short)f2bf(afx[s].z); v[3] = (short)f2bf(afx[s].w);
      v[4] = (short)f2bf(afy[s].x); v[5] = (short)f2bf(afy[s].y);
      v[6] = (short)f2bf(afy[s].z); v[7] = (short)f2bf(afy[s].w);
    } else {
      const float c = coef4[kt];
#pragma unroll
      for (int e = 0; e < 8; ++e)
        v[e] = (short)f2bf(b2f((unsigned short)av[s][e]) * c);
    }
    *(bf16x8*)&lds[buf * 8192 + a_dst] = v;
  };
  auto compute = [&](int buf) {
    const int base = buf * 8192;
    bf16x8 a[4], b[2];
#pragma unroll
    for (int mf = 0; mf < 4; ++mf) {
      const int row = wm * 64 + mf * 16 + l16;
      a[mf] = *(const bf16x8*)&lds[base + row * 32 + ((kg ^ sr_rd) << 3)];
    }
#pragma unroll
    for (int nf = 0; nf < 2; ++nf) {
      const int row = wn * 32 + nf * 16 + l16;
      b[nf] = *(const bf16x8*)&lds[base + 4096 + row * 32 + ((kg ^ sr_rd) << 3)];
    }
#pragma unroll
    for (int mf = 0; mf < 4; ++mf)
#pragma unroll
      for (int nf = 0; nf < 2; ++nf)
        acc[mf][nf] =
            __builtin_amdgcn_mfma_f32_16x16x32_bf16(a[mf], b[nf], acc[mf][nf], 0, 0, 0);
  };

  // ---- prologue: 2 tiles in flight ----
  issueA(0, 0, 0); issueB(0, 0);
  issueA(1, 1, 1); issueB(1, 1);
  if constexpr (AMODE != 2) writeA(0, 0, 0);

  // ---- counted-vmcnt pipelined K-loop (T3+T4) ----
#pragma unroll
  for (int t = 0; t < KSTEPS; ++t) {
    if (t < KSTEPS - 1) {
      if constexpr (AMODE == 0) WAIT_VMCNT3(); else WAIT_VMCNT2();
    } else {
      WAIT_VMCNT0();
    }
    WAIT_LGKM0();                       // own writeA(t) committed
    __builtin_amdgcn_s_barrier();       // all waves: buf[t%3] valid
    __builtin_amdgcn_sched_barrier(0);
    if (t + 2 < KSTEPS) {               // prefetch into buf[(t-1)%3] (free now)
      issueA(t + 2, t & 1, (t + 2) % 3);
      issueB(t + 2, (t + 2) % 3);
    }
    compute(t % 3);
    if constexpr (AMODE != 2) {
      if (t + 1 < KSTEPS) writeA(t + 1, (t + 1) & 1, (t + 1) % 3);
    }
  }
  __syncthreads();

  float* scratch = (float*)lds;

  // ---- epilogue ----
  if constexpr (EPI == 0) {
#pragma unroll
    for (int mf = 0; mf < 4; ++mf) {
#pragma unroll
      for (int j = 0; j < 4; ++j) {
        const int row = mblk * 128 + wm * 64 + mf * 16 + kg * 4 + j;
        unsigned short* dr = Dbf + (size_t)row * NOUT + nblk * 128 + wn * 32 + l16;
#pragma unroll
        for (int nf = 0; nf < 2; ++nf)
          dr[nf * 16] = f2bf(acc[mf][nf][j]);
      }
    }
  } else if constexpr (EPI == 1) {
    // scatter + block column sums
    if (tid < 256) scratch[tid] = 0.0f;
    __syncthreads();
    const int b0 = (mblk * 128) / NT;
#pragma unroll
    for (int mf = 0; mf < 4; ++mf) {
      const int baser = mblk * 128 + wm * 64 + mf * 16 + kg * 4;
      const int bb = baser / NT;          // uniform over j (NT % 4 == 0)
      const int bsel = (bb != b0) ? 1 : 0;
      float s[2] = {0.0f, 0.0f};
#pragma unroll
      for (int j = 0; j < 4; ++j) {
        const int row = baser + j;
        const int pix = pixw[row];
        float* dr = aux + ((size_t)bb * HWHW + pix) * 128 + wn * 32 + l16;
#pragma unroll
        for (int nf = 0; nf < 2; ++nf) {
          atomicAdd(dr + nf * 16, acc[mf][nf][j]);
          s[nf] += acc[mf][nf][j];
        }
      }
#pragma unroll
      for (int nf = 0; nf < 2; ++nf)
        atomicAdd(&scratch[bsel * 128 + wn * 32 + nf * 16 + l16], s[nf]);
    }
    __syncthreads();
    const int b1 = (mblk * 128 + 127) / NT;
    if (tid < 128) atomicAdd(meanr + (size_t)b0 * 128 + tid, scratch[tid]);
    else if (tid < 256 && b1 != b0)
      atomicAdd(meanr + (size_t)b1 * 128 + (tid - 128), scratch[tid]);
  } else {
    // EPI 2: logits. Wave's 32-col span = head wn. Reduce over l16 group.
    float bv[2];
#pragma unroll
    for (int nf = 0; nf < 2; ++nf)
      bv[nf] = bias[wn * 32 + nf * 16 + l16];
#pragma unroll
    for (int mf = 0; mf < 4; ++mf) {
#pragma unroll
      for (int j = 0; j < 4; ++j) {
        const int rl = wm * 64 + mf * 16 + kg * 4 + j;
        const int row = mblk * 128 + rl;
        const unsigned short* kr = kvb + (size_t)row * 256 + wn * 32 + l16;
        float s = (acc[mf][0][j] + bv[0]) * b2f(kr[0]) +
                  (acc[mf][1][j] + bv[1]) * b2f(kr[16]);
        s += __shfl_xor(s, 8, 16); s += __shfl_xor(s, 4, 16);
        s += __shfl_xor(s, 2, 16); s += __shfl_xor(s, 1, 16);
        if (l16 == 0) scratch[rl * 4 + wn] = s;
      }
    }
    __syncthreads();
    if (tid < 128) {
      const int row = mblk * 128 + tid;
      const int bb = row / NT, n = row - bb * NT;
#pragma unroll
      for (int h = 0; h < 4; ++h)
        aux[((size_t)bb * NHEADS + h) * NT + n] = scratch[tid * 4 + h] * SCALE_C;
    }
  }
}

// ---------------------------------------------------------------------------
// k_smpart: per-(bh, chunk) partial max & sum-exp.  NT = 8 * 2500.
// ---------------------------------------------------------------------------
__global__ __launch_bounds__(256) void k_smpart(
    const float* __restrict__ logits, float* __restrict__ pm,
    float* __restrict__ ps)
{
  const int ch = blockIdx.x, bh = blockIdx.y;
  const float* L = logits + (size_t)bh * NT + ch * 2500;
  const int tid = threadIdx.x;
  __shared__ float sred[4];

  float m = -INFINITY;
  for (int i = tid; i < 2500; i += 256) m = fmaxf(m, L[i]);
  m = warpMax(m);
  if ((tid & 63) == 0) sred[tid >> 6] = m;
  __syncthreads();
  m = fmaxf(fmaxf(sred[0], sred[1]), fmaxf(sred[2], sred[3]));

  float s = 0.0f;
  for (int i = tid; i < 2500; i += 256) s += __expf(L[i] - m);
  s = warpSum(s);
  __syncthreads();
  if ((tid & 63) == 0) sred[tid >> 6] = s;
  __syncthreads();
  if (tid == 0) {
    pm[bh * 8 + ch] = m;
    ps[bh * 8 + ch] = sred[0] + sred[1] + sred[2] + sred[3];
  }
}

// ---------------------------------------------------------------------------
// k_cntfix: block b: cnt[b] = #hit pixels. Block 0 also combines softmax
// partials -> smM, smSinv.
// ---------------------------------------------------------------------------
__global__ __launch_bounds__(256) void k_cntfix(
    const float* __restrict__ hits, float* __restrict__ cnt,
    const float* __restrict__ pm, const float* __restrict__ ps,
    float* __restrict__ smM, float* __restrict__ smSinv)
{
  const int b = blockIdx.x;
  const int tid = threadIdx.x;
  float s = 0.0f;
  for (int i = tid; i < HWHW; i += 256)
    s += (hits[(size_t)b * HWHW + i] > 0.0f) ? 1.0f : 0.0f;
  s = warpSum(s);
  __shared__ float sred[4];
  if ((tid & 63) == 0) sred[tid >> 6] = s;
  __syncthreads();
  if (tid == 0) cnt[b] = sred[0] + sred[1] + sred[2] + sred[3];
  if (b == 0 && tid < BB * NHEADS) {
    float M = -INFINITY;
#pragma unroll
    for (int c = 0; c < 8; ++c) M = fmaxf(M, pm[tid * 8 + c]);
    float S = 0.0f;
#pragma unroll
    for (int c = 0; c < 8; ++c) S += ps[tid * 8 + c] * __expf(pm[tid * 8 + c] - M);
    smM[tid] = M;
    smSinv[tid] = 1.0f / S;
  }
}

// ---------------------------------------------------------------------------
// k_final: out[b][c][hw] = lidar + (delta[b][hw][c] - mean*mask)*alpha*gamma
// 80px x 128ch tiles, 512 threads; hits-gated delta reads; XOR-swizzled LDS.
// ---------------------------------------------------------------------------
__global__ __launch_bounds__(512) void k_final(
    const float* __restrict__ lidar, const float* __restrict__ alpha,
    const float* __restrict__ hits, const float* __restrict__ mean_raw,
    const float* __restrict__ cnt, const float* __restrict__ delta,
    float* __restrict__ out)
{
  __shared__ float tile[80 * 136];
  const int b = blockIdx.y;
  const int p0 = blockIdx.x * 80;
  const int t = threadIdx.x;
  const float4* dsrc = (const float4*)(delta + ((size_t)b * HWHW + p0) * 128);
  const float* hrow = hits + (size_t)b * HWHW + p0;
#pragma unroll
  for (int i = 0; i < 5; ++i) {
    const int idx4 = i * 512 + t;         // 2560 float4 = 80px * 32
    const int p = idx4 >> 5, c4 = idx4 & 31;
    float4 f = make_float4(0.0f, 0.0f, 0.0f, 0.0f);
    if (hrow[p] > 0.0f) f = dsrc[idx4];
    *(float4*)&tile[p * 136 + ((c4 ^ (p & 7)) << 2)] = f;
  }
  __syncthreads();
  const int c = t >> 2, sub = t & 3;
  const int cq = c >> 2, cr = c & 3;
  const float mn = mean_raw[b * 128 + c] / (cnt[b] + EPS_C);
  const size_t cbase = ((size_t)b * CC + c) * HWHW + p0;
  const size_t hbase = (size_t)b * HWHW + p0;
#pragma unroll
  for (int j = 0; j < 5; ++j) {
    const int pq = j * 16 + sub * 4;
    float4 d;
    d.x = tile[(pq + 0) * 136 + (((cq ^ ((pq + 0) & 7)) << 2) | cr)];
    d.y = tile[(pq + 1) * 136 + (((cq ^ ((pq + 1) & 7)) << 2) | cr)];
    d.z = tile[(pq + 2) * 136 + (((cq ^ ((pq + 2) & 7)) << 2) | cr)];
    d.w = tile[(pq + 3) * 136 + (((cq ^ ((pq + 3) & 7)) << 2) | cr)];
    const float4 li = *(const float4*)(lidar + cbase + pq);
    const float4 al = *(const float4*)(alpha + p0 + pq);
    const float4 ht = *(const float4*)(hits + hbase + pq);
    float4 o;
    o.x = li.x + (d.x - (ht.x > 0.0f ? mn : 0.0f)) * al.x * GAMMA_C;
    o.y = li.y + (d.y - (ht.y > 0.0f ? mn : 0.0f)) * al.y * GAMMA_C;
    o.z = li.z + (d.z - (ht.z > 0.0f ? mn : 0.0f)) * al.z * GAMMA_C;
    o.w = li.w + (d.w - (ht.w > 0.0f ? mn : 0.0f)) * al.w * GAMMA_C;
    *(float4*)(out + cbase + pq) = o;
  }
}

// ---------------------------------------------------------------------------
extern "C" void kernel_launch(void* const* d_in, const int* in_sizes, int n_in,
                              void* d_out, int out_size, void* d_ws, size_t ws_size,
                              hipStream_t stream)
{
  const float* lidar  = (const float*)d_in[0];
  const float* tokens = (const float*)d_in[1];
  const float* gate   = (const float*)d_in[2];
  const float* alpha  = (const float*)d_in[3];
  const float* q_w    = (const float*)d_in[4];
  const float* q_b    = (const float*)d_in[5];
  const float* k_w    = (const float*)d_in[6];
  const float* v_w    = (const float*)d_in[7];
  const float* out_w  = (const float*)d_in[8];
  const int*   cidx   = (const int*)d_in[9];
  float* out = (float*)d_out;

  char* W = (char*)d_ws;
  // kv_bf [80000][256] bf16 (K cols 0..127, V cols 128..255)
  unsigned short* kv_bf = (unsigned short*)(W + 0);                 // 40,960,000
  // delta [B][HW][128] f32 (66,355,200). lidar_t aliases within; it is dead
  // before k_zero touches delta.
  float* delta = (float*)(W + 61440000);
  unsigned short* lidar_t = (unsigned short*)(W + 81920000);
  float* logits   = (float*)(W + 127795200);   // 1,280,000
  int*   pix_ws   = (int*)(W + 129075200);     //   320,000
  float* hits     = (float*)(W + 129395200);   //   518,400
  float* mean_raw = (float*)(W + 129913600);   //     2,048
  float* cnt      = (float*)(W + 129915648);   //        64
  unsigned short* kvw_bf = (unsigned short*)(W + 129915712);  // 131,072
  unsigned short* qw_bf  = (unsigned short*)(W + 130046784);  //  32,768
  unsigned short* ow_bf  = (unsigned short*)(W + 130079552);  //  32,768
  float* pm     = (float*)(W + 130112320);     // 512
  float* ps     = (float*)(W + 130112832);     // 512
  float* smM    = (float*)(W + 130113344);     // 64
  float* smSinv = (float*)(W + 130113408);     // 64

  hipMemsetAsync(hits, 0, (size_t)BB * HWHW * sizeof(float), stream);
  hipMemsetAsync(mean_raw, 0, 2048 + 64, stream);

  k_prep_pix<<<dim3(409), 256, 0, stream>>>(k_w, v_w, q_w, out_w, kvw_bf,
                                            qw_bf, ow_bf, cidx, pix_ws, hits);
  k_tr2<<<dim3(127, BB, 2), 256, 0, stream>>>(lidar, lidar_t);
  // kv projection: [80000,256] x [256,256]^T -> kv_bf
  k_pipe<8, 256, 0, 0, 256><<<dim3(625, 2), 512, 0, stream>>>(
      tokens, nullptr, kvw_bf, nullptr, kv_bf, nullptr, nullptr, nullptr,
      nullptr, nullptr, nullptr, nullptr, nullptr);
  // q projection (rows gathered from lidar_t) -> per-head logits directly
  k_pipe<4, 128, 2, 2, 128><<<dim3(625, 1), 512, 0, stream>>>(
      nullptr, lidar_t, qw_bf, q_b, nullptr, pix_ws, logits, kv_bf,
      nullptr, nullptr, nullptr, nullptr, nullptr);
  // lidar_t dead from here: zero only hit delta rows
  k_zero<<<dim3(10000), 256, 0, stream>>>(pix_ws, delta);
  k_smpart<<<dim3(8, BB * NHEADS), 256, 0, stream>>>(logits, pm, ps);
  k_cntfix<<<dim3(BB), 256, 0, stream>>>(hits, cnt, pm, ps, smM, smSinv);
  // out projection with fused attention-weighted V + scatter + mean accum
  k_pipe<4, 128, 3, 1, 128><<<dim3(625, 1), 512, 0, stream>>>(
      nullptr, kv_bf, ow_bf, nullptr, nullptr, pix_ws, delta, nullptr,
      mean_raw, smM, smSinv, gate, logits);
  k_final<<<dim3(405, BB), 512, 0, stream>>>(lidar, alpha, hits, mean_raw, cnt,
                                             delta, out);
}